// Round 16
// baseline (193.891 us; speedup 1.0000x reference)
//
#include <hip/hip_runtime.h>

// RetinaNet matcher: gt_boxes [B=8, G=64, 4] f32, anchors [A=120000, 4] f32.
// Outputs (concat in d_out, f32): matched_idxs [B,A] (as float), matched_vals [B,A].
//
// Numerics: bit-exact vs np (absmax 0.0 R5-R15). opaque() barriers on every
// mul result -> no FMA-contraction site. div_rn() = correctly-rounded divide
// for mid-range operands (== v_div expansion with scale==1). argmax
// tie-break = first g (strict >). IoU >= 0 -> uint atomicMax bit-exact.
//
// R16 = R14 (proven 76 us structure) + spatial sort + wave ballot-skip.
// R15 showed VALU-busy is work-proportional (~53 us dense floor); only
// removing work helps. ~95% of (wave,g) iters have zero intersection for
// all lanes once anchors are spatially sorted. Fixes for R7's failure:
//  - anchors MATERIALIZED in sorted order (coalesced loads; orig[] kept
//    for one final scatter) instead of per-load perm gather;
//  - pass2 = R14's E-mask fixup (no recompute), so no pass2 blowup.
// Skip exactness: skipped (wave,g) => all q==+0.0 => sred[g] stays 0 =
// true block max (E-chain q <= m_block <= hpg intact); vmax strict-> and
// amax init 0 unchanged (np.argmax of all-zero row = 0). Sort order is
// outcome-invariant: per-anchor results self-contained, maxes order-free,
// outputs relabeled via orig[]. Fallback: unsorted R14 path if ws small.

static constexpr int G = 64;
static constexpr int NCELL = 256;   // 16x16 grid of 50px cells

__device__ __forceinline__ float opaque(float x) {
    asm volatile("" : "+v"(x));  // no-op; blocks FMA contraction across x
    return x;
}

__device__ __forceinline__ int vindex(int i) {
    asm volatile("" : "+v"(i));  // force VGPR residency; defeats scalarization
    return i;
}

__device__ __forceinline__ float box_area(float x1, float y1, float x2, float y2) {
    return opaque(__fmul_rn(__fsub_rn(x2, x1), __fsub_rn(y2, y1)));
}

__device__ __forceinline__ float inter_area(float gx1, float gy1, float gx2, float gy2,
                                            float ax1, float ay1, float ax2, float ay2) {
    float ltx = fmaxf(gx1, ax1);
    float lty = fmaxf(gy1, ay1);
    float rbx = fminf(gx2, ax2);
    float rby = fminf(gy2, ay2);
    float w = fmaxf(__fsub_rn(rbx, ltx), 0.0f);
    float h = fmaxf(__fsub_rn(rby, lty), 0.0f);
    return opaque(__fmul_rn(w, h));
}

// Correctly-rounded f32 divide for mid-range operands (no denormal/overflow).
__device__ __forceinline__ float div_rn(float n, float d) {
    float r = __builtin_amdgcn_rcpf(d);
    float e = fmaf(-d, r, 1.0f);
    r = fmaf(e, r, r);
    float q = __fmul_rn(n, r);
    float s = fmaf(-d, q, n);
    q = fmaf(s, r, q);
    s = fmaf(-d, q, n);
    q = fmaf(s, r, q);
    return q;
}

#define DPP_MAX_STAGE(x, ctrl)                                                   \
    do {                                                                         \
        int _yi = __builtin_amdgcn_update_dpp(__float_as_int(x),                 \
                                              __float_as_int(x), (ctrl),         \
                                              0xf, 0xf, false);                  \
        (x) = fmaxf((x), __int_as_float(_yi));                                   \
    } while (0)

// Full wave64 max; result valid in lane 63.
__device__ __forceinline__ float wave_max_lane63(float x) {
    DPP_MAX_STAGE(x, 0xB1);   // quad_perm xor1
    DPP_MAX_STAGE(x, 0x4E);   // quad_perm xor2
    DPP_MAX_STAGE(x, 0x141);  // row_half_mirror
    DPP_MAX_STAGE(x, 0x140);  // row_mirror
    DPP_MAX_STAGE(x, 0x142);  // row_bcast15
    DPP_MAX_STAGE(x, 0x143);  // row_bcast31
    return x;
}

// hpg[i] = 0 bits (+0.0f) and gt-area cache for all (b,g).
__global__ void k_init(const float* __restrict__ gt, unsigned int* __restrict__ hpg,
                       float* __restrict__ gab, int BG) {
    int i = blockIdx.x * 256 + threadIdx.x;
    if (i < BG) {
        hpg[i] = 0u;
        float4 gb = ((const float4*)gt)[i];
        gab[i] = box_area(gb.x, gb.y, gb.z, gb.w);
    }
}

__device__ __forceinline__ int cell_of(float4 ab) {
    float cx = (ab.x + ab.z) * 0.5f;   // binning only; precision irrelevant
    float cy = (ab.y + ab.w) * 0.5f;
    int cxi = (int)(cx * 0.02f); cxi = cxi < 0 ? 0 : (cxi > 15 ? 15 : cxi);
    int cyi = (int)(cy * 0.02f); cyi = cyi < 0 ? 0 : (cyi > 15 ? 15 : cyi);
    return cyi * 16 + cxi;
}

__global__ void k_cell(const float* __restrict__ anchors,
                       unsigned int* __restrict__ hist, int A) {
    int a = blockIdx.x * 256 + threadIdx.x;
    if (a >= A) return;
    atomicAdd(&hist[cell_of(((const float4*)anchors)[a])], 1u);
}

__global__ void k_scan(const unsigned int* __restrict__ hist,
                       unsigned int* __restrict__ offs) {
    __shared__ unsigned int s[NCELL];
    int t = threadIdx.x;
    unsigned int v = hist[t];
    s[t] = v;
    __syncthreads();
    for (int d = 1; d < NCELL; d <<= 1) {
        unsigned int add = (t >= d) ? s[t - d] : 0u;
        __syncthreads();
        s[t] += add;
        __syncthreads();
    }
    offs[t] = s[t] - v;   // exclusive prefix
}

__global__ void k_scatter(const float* __restrict__ anchors,
                          const unsigned int* __restrict__ offs,
                          unsigned int* __restrict__ cursor,
                          float* __restrict__ sortedA,
                          int* __restrict__ orig, int A) {
    int a = blockIdx.x * 256 + threadIdx.x;
    if (a >= A) return;
    float4 ab = ((const float4*)anchors)[a];
    int c = cell_of(ab);
    unsigned int pos = offs[c] + atomicAdd(&cursor[c], 1u);
    ((float4*)sortedA)[pos] = ab;
    orig[pos] = a;
}

// Pass 1 (R14 structure + ballot skip): 4 anchors/thread, g-outer, DPP wave
// max, LDS block max. STORE: per-anchor vmax/amax (sorted idx), sred dump.
// Grid: (nchunks = ceil(A/1024), B), block 256.
template <bool STORE>
__global__ __launch_bounds__(256, 4)
void pass1_k(const float* __restrict__ gt,
             const float* __restrict__ anchors,
             const float* __restrict__ gab,
             unsigned int* __restrict__ hpg,
             unsigned int* __restrict__ sredg,
             float* __restrict__ vmaxA,
             int* __restrict__ amaxA,
             int A, int nchunks) {
    const int b = blockIdx.y;
    const int t = threadIdx.x;

    __shared__ unsigned int sred[G];
    if (t < G) sred[t] = 0u;
    __syncthreads();

    const int base = blockIdx.x * 1024;
    float ax1[4], ay1[4], ax2[4], ay2[4], aar[4];
    bool val[4];
#pragma unroll
    for (int k = 0; k < 4; ++k) {
        int a = base + k * 256 + t;
        val[k] = (a < A);
        float4 ab = ((const float4*)anchors)[val[k] ? a : 0];
        ax1[k] = val[k] ? ab.x : -3.0e38f;   // degenerate -> inter==+0, q==+0
        ay1[k] = val[k] ? ab.y : -3.0e38f;
        ax2[k] = val[k] ? ab.z : -3.0e38f;
        ay2[k] = val[k] ? ab.w : -3.0e38f;
        aar[k] = box_area(ax1[k], ay1[k], ax2[k], ay2[k]);
    }

    const float4* gtb = (const float4*)gt + (size_t)b * G;
    const float* gas = gab + b * G;

    float vmax[4] = {0.0f, 0.0f, 0.0f, 0.0f};
    int amax[4] = {0, 0, 0, 0};

#pragma unroll 4
    for (int g = 0; g < G; ++g) {
        const int gv = vindex(g);              // VMEM broadcast (L1-hot)
        const float4 gb = gtb[gv];
        const float ga = gas[gv];
        float inter[4];
#pragma unroll
        for (int k = 0; k < 4; ++k)
            inter[k] = inter_area(gb.x, gb.y, gb.z, gb.w,
                                  ax1[k], ay1[k], ax2[k], ay2[k]);
        float itest = fmaxf(fmaxf(inter[0], inter[1]),
                            fmaxf(inter[2], inter[3]));
        // Wave-uniform skip: all lanes' q would be +0.0 exactly -> sred
        // (init 0) stays the true block max; vmax/amax strict-> unchanged.
        if (__any(itest > 0.0f)) {
            float m = 0.0f;
#pragma unroll
            for (int k = 0; k < 4; ++k) {
                float denom = __fsub_rn(__fadd_rn(ga, aar[k]), inter[k]);
                float q = div_rn(inter[k], denom);
                if constexpr (STORE) {
                    if (q > vmax[k]) { vmax[k] = q; amax[k] = g; }  // first-max
                }
                m = fmaxf(m, q);
            }
            m = wave_max_lane63(m);
            if ((t & 63) == 63)
                atomicMax(&sred[g], __float_as_uint(m));
        }
    }

    if constexpr (STORE) {
#pragma unroll
        for (int k = 0; k < 4; ++k) {
            if (!val[k]) continue;
            size_t idx = (size_t)b * A + (base + k * 256 + t);
            vmaxA[idx] = vmax[k];
            amaxA[idx] = amax[k];
        }
    }

    __syncthreads();
    if (t < G) {
        atomicMax(&hpg[b * G + t], sred[t]);
        if constexpr (STORE)
            sredg[(size_t)(b * nchunks + blockIdx.x) * G + t] = sred[t];
    }
}

// Pass 2 (R14 E-mask fixup + scatter to orig order). Grid: (nchunks, B).
template <bool SCATTER>
__global__ __launch_bounds__(256, 8)
void pass2_lite(const float* __restrict__ gt,
                const float* __restrict__ anchors,
                const float* __restrict__ gab,
                const unsigned int* __restrict__ hpg,
                const unsigned int* __restrict__ sredg,
                const float* __restrict__ vmaxA,
                const int* __restrict__ amaxA,
                const int* __restrict__ orig,
                float* __restrict__ out_idx,
                float* __restrict__ out_val,
                int A, int nchunks) {
    const int b = blockIdx.y;
    const int t = threadIdx.x;
    const int base = blockIdx.x * 1024;

    const unsigned int* sb = sredg + (size_t)(b * nchunks + blockIdx.x) * G;
    const unsigned int* hb = hpg + b * G;

    unsigned long long E = 0ull;
#pragma unroll 16
    for (int g = 0; g < G; ++g)
        E |= (sb[g] == hb[g]) ? (1ull << g) : 0ull;

    bool pu[4] = {false, false, false, false};

    if (E != 0ull) {                    // rare; block-uniform branch
        const float4* gtb = (const float4*)gt + (size_t)b * G;
        const float* gas = gab + b * G;
        float ax1[4], ay1[4], ax2[4], ay2[4], aar[4];
#pragma unroll
        for (int k = 0; k < 4; ++k) {
            int a = base + k * 256 + t;
            bool v = (a < A);
            float4 ab = ((const float4*)anchors)[v ? a : 0];
            ax1[k] = v ? ab.x : -3.0e38f;
            ay1[k] = v ? ab.y : -3.0e38f;
            ax2[k] = v ? ab.z : -3.0e38f;
            ay2[k] = v ? ab.w : -3.0e38f;
            aar[k] = box_area(ax1[k], ay1[k], ax2[k], ay2[k]);
        }
        unsigned long long e = E;
        while (e) {
            int g = __builtin_ctzll(e);
            e &= e - 1;
            float4 gb = gtb[g];
            float ga = gas[g];
            float hgf = __uint_as_float(hb[g]);
#pragma unroll
            for (int k = 0; k < 4; ++k) {
                float inter = inter_area(gb.x, gb.y, gb.z, gb.w,
                                         ax1[k], ay1[k], ax2[k], ay2[k]);
                float denom = __fsub_rn(__fadd_rn(ga, aar[k]), inter);
                float q = div_rn(inter, denom);
                pu[k] = pu[k] | (q == hgf);
            }
        }
    }

#pragma unroll
    for (int k = 0; k < 4; ++k) {
        int a = base + k * 256 + t;
        if (a >= A) continue;
        size_t idx = (size_t)b * A + a;
        float vm = vmaxA[idx];
        int am = amaxA[idx];
        int m;
        if (pu[k]) {
            m = am;                          // low-quality match recovery
        } else if (vm < 0.4f) {
            m = -1;                          // BELOW_LOW_QUALITY
        } else if (vm < 0.5f) {
            m = -2;                          // BETWEEN_THRESHOLDS
        } else {
            m = am;
        }
        size_t o = SCATTER ? ((size_t)b * A + orig[a]) : idx;
        out_idx[o] = (float)m;
        out_val[o] = vm;
    }
}

extern "C" void kernel_launch(void* const* d_in, const int* in_sizes, int n_in,
                              void* d_out, int out_size, void* d_ws, size_t ws_size,
                              hipStream_t stream) {
    const float* gt = (const float*)d_in[0];
    const float* anchors = (const float*)d_in[1];
    const int BG = in_sizes[0] / 4;   // B*G = 512
    const int B = BG / G;             // 8
    const int A = in_sizes[1] / 4;    // 120000

    const int nchunks = (A + 1023) / 1024;

    // ws layout (u32 units):
    // [0,512) hpg | [512,1024) gab | [1024,1280) hist | [1280,1536) cursor |
    // [1536,1792) offs | [1792, +4A) sortedA (16B-aligned) | [+A) orig |
    // [+nchunks*B*64) sredg | vmaxA[B*A] | amaxA[B*A]
    unsigned int* ws = (unsigned int*)d_ws;
    unsigned int* hpg = ws;
    float* gab = (float*)(ws + 512);
    unsigned int* hist = ws + 1024;
    unsigned int* cursor = ws + 1280;
    unsigned int* offs = ws + 1536;
    float* sortedA = (float*)(ws + 1792);
    int* orig = (int*)(ws + 1792 + 4 * (size_t)A);
    unsigned int* sredg = ws + 1792 + 5 * (size_t)A;
    size_t voff = 1792 + 5 * (size_t)A + (size_t)nchunks * B * G;
    float* vmaxA = (float*)(ws + voff);
    int* amaxA = (int*)(vmaxA + (size_t)B * A);
    const size_t need = (voff + 2 * (size_t)B * A) * 4;
    const bool sorted = (ws_size >= need);

    float* out_idx = (float*)d_out;
    float* out_val = out_idx + (size_t)B * A;

    k_init<<<(BG + 255) / 256, 256, 0, stream>>>(gt, hpg, gab, BG);

    dim3 g1(nchunks, B);
    if (sorted) {
        hipMemsetAsync(hist, 0, 512 * 4, stream);   // hist + cursor
        k_cell<<<(A + 255) / 256, 256, 0, stream>>>(anchors, hist, A);
        k_scan<<<1, NCELL, 0, stream>>>(hist, offs);
        k_scatter<<<(A + 255) / 256, 256, 0, stream>>>(anchors, offs, cursor,
                                                       sortedA, orig, A);
        pass1_k<true><<<g1, 256, 0, stream>>>(gt, sortedA, gab, hpg, sredg,
                                              vmaxA, amaxA, A, nchunks);
        pass2_lite<true><<<g1, 256, 0, stream>>>(gt, sortedA, gab, hpg, sredg,
                                                 vmaxA, amaxA, orig,
                                                 out_idx, out_val, A, nchunks);
    } else {
        // Fallback: R14 unsorted path (needs only sredg+vmax+amax; identity order)
        pass1_k<true><<<g1, 256, 0, stream>>>(gt, anchors, gab, hpg, sredg,
                                              vmaxA, amaxA, A, nchunks);
        pass2_lite<false><<<g1, 256, 0, stream>>>(gt, anchors, gab, hpg, sredg,
                                                  vmaxA, amaxA, orig,
                                                  out_idx, out_val, A, nchunks);
    }
}

// Round 17
// 108.257 us; speedup vs baseline: 1.7910x; 1.7910x over previous
//
#include <hip/hip_runtime.h>

// RetinaNet matcher: gt_boxes [B=8, G=64, 4] f32, anchors [A=120000, 4] f32.
// Outputs (concat in d_out, f32): matched_idxs [B,A] (as float), matched_vals [B,A].
//
// Numerics: bit-exact vs np (absmax 0.0 R5-R16, incl. the sorted path in R16).
// opaque() barriers on every mul -> no FMA-contraction site. div_rn() =
// correctly-rounded divide for mid-range operands. argmax tie-break = first g
// (strict >). IoU >= 0 -> uint atomicMax bit-exact.
//
// R17: R16 was correct but k_scatter burned 59 us on 120k global atomicAdds
// ping-ponging 16 cache lines across 8 XCDs. Replace with an atomic-free
// counting sort: k_count (per-block LDS hist -> bh[blk][c]), k_colscan
// (1 block: per-cell exclusive prefix across blocks + scan of totals ->
// cellBase), k_scat (LDS rank + computed base; ZERO global atomics).
// LDS-rank order nondeterminism is output-invariant (per-anchor results
// self-contained, maxes order-free, E-recompute exact per block, outputs
// relabeled via orig[]) - verified empirically by R16's absmax 0.0.
// pass1 skip upgraded: wave-bbox (DPP-reduced once, ->SGPR) pre-test per g
// skips the whole ~100-op body; inner ballot still skips the div tail.
// Skipped (wave,g): all q == +0.0 exactly -> sred stays true block max.

static constexpr int G = 64;
static constexpr int NCELL = 256;   // 16x16 grid of 50px cells

__device__ __forceinline__ float opaque(float x) {
    asm volatile("" : "+v"(x));  // no-op; blocks FMA contraction across x
    return x;
}

__device__ __forceinline__ int vindex(int i) {
    asm volatile("" : "+v"(i));  // force VGPR residency; defeats scalarization
    return i;
}

__device__ __forceinline__ float box_area(float x1, float y1, float x2, float y2) {
    return opaque(__fmul_rn(__fsub_rn(x2, x1), __fsub_rn(y2, y1)));
}

__device__ __forceinline__ float inter_area(float gx1, float gy1, float gx2, float gy2,
                                            float ax1, float ay1, float ax2, float ay2) {
    float ltx = fmaxf(gx1, ax1);
    float lty = fmaxf(gy1, ay1);
    float rbx = fminf(gx2, ax2);
    float rby = fminf(gy2, ay2);
    float w = fmaxf(__fsub_rn(rbx, ltx), 0.0f);
    float h = fmaxf(__fsub_rn(rby, lty), 0.0f);
    return opaque(__fmul_rn(w, h));
}

// Correctly-rounded f32 divide for mid-range operands (no denormal/overflow).
__device__ __forceinline__ float div_rn(float n, float d) {
    float r = __builtin_amdgcn_rcpf(d);
    float e = fmaf(-d, r, 1.0f);
    r = fmaf(e, r, r);
    float q = __fmul_rn(n, r);
    float s = fmaf(-d, q, n);
    q = fmaf(s, r, q);
    s = fmaf(-d, q, n);
    q = fmaf(s, r, q);
    return q;
}

#define DPP_MAX_STAGE(x, ctrl)                                                   \
    do {                                                                         \
        int _yi = __builtin_amdgcn_update_dpp(__float_as_int(x),                 \
                                              __float_as_int(x), (ctrl),         \
                                              0xf, 0xf, false);                  \
        (x) = fmaxf((x), __int_as_float(_yi));                                   \
    } while (0)

#define DPP_MIN_STAGE(x, ctrl)                                                   \
    do {                                                                         \
        int _yi = __builtin_amdgcn_update_dpp(__float_as_int(x),                 \
                                              __float_as_int(x), (ctrl),         \
                                              0xf, 0xf, false);                  \
        (x) = fminf((x), __int_as_float(_yi));                                   \
    } while (0)

// Full wave64 max; result valid in lane 63.
__device__ __forceinline__ float wave_max_lane63(float x) {
    DPP_MAX_STAGE(x, 0xB1);   // quad_perm xor1
    DPP_MAX_STAGE(x, 0x4E);   // quad_perm xor2
    DPP_MAX_STAGE(x, 0x141);  // row_half_mirror
    DPP_MAX_STAGE(x, 0x140);  // row_mirror
    DPP_MAX_STAGE(x, 0x142);  // row_bcast15
    DPP_MAX_STAGE(x, 0x143);  // row_bcast31
    return x;
}

__device__ __forceinline__ float wave_min_lane63(float x) {
    DPP_MIN_STAGE(x, 0xB1);
    DPP_MIN_STAGE(x, 0x4E);
    DPP_MIN_STAGE(x, 0x141);
    DPP_MIN_STAGE(x, 0x140);
    DPP_MIN_STAGE(x, 0x142);
    DPP_MIN_STAGE(x, 0x143);
    return x;
}

__device__ __forceinline__ float lane63_bcast(float x) {
    return __int_as_float(__builtin_amdgcn_readlane(__float_as_int(x), 63));
}

// hpg[i] = 0 bits (+0.0f) and gt-area cache for all (b,g).
__global__ void k_init(const float* __restrict__ gt, unsigned int* __restrict__ hpg,
                       float* __restrict__ gab, int BG) {
    int i = blockIdx.x * 256 + threadIdx.x;
    if (i < BG) {
        hpg[i] = 0u;
        float4 gb = ((const float4*)gt)[i];
        gab[i] = box_area(gb.x, gb.y, gb.z, gb.w);
    }
}

__device__ __forceinline__ int cell_of(float4 ab) {
    float cx = (ab.x + ab.z) * 0.5f;   // binning only; precision irrelevant
    float cy = (ab.y + ab.w) * 0.5f;
    int cxi = (int)(cx * 0.02f); cxi = cxi < 0 ? 0 : (cxi > 15 ? 15 : cxi);
    int cyi = (int)(cy * 0.02f); cyi = cyi < 0 ? 0 : (cyi > 15 ? 15 : cyi);
    return cyi * 16 + cxi;
}

// Sort step 1: per-block LDS histogram -> bh[blk*256 + c] (coalesced write).
__global__ void k_count(const float* __restrict__ anchors,
                        unsigned int* __restrict__ bh, int A) {
    __shared__ unsigned int h[NCELL];
    int t = threadIdx.x;
    h[t] = 0u;
    __syncthreads();
    int a = blockIdx.x * 256 + t;
    if (a < A) atomicAdd(&h[cell_of(((const float4*)anchors)[a])], 1u);
    __syncthreads();
    bh[(size_t)blockIdx.x * 256 + t] = h[t];
}

// Sort step 2 (ONE block, 256 threads): per-cell exclusive prefix across
// blocks (bh[blk][c] -> #earlier anchors of cell c) + cellBase scan.
__global__ void k_colscan(unsigned int* __restrict__ bh,
                          unsigned int* __restrict__ cellBase, int NB) {
    const int c = threadIdx.x;
    unsigned int s = 0u;
#pragma unroll 4
    for (int blk = 0; blk < NB; ++blk) {
        size_t i = (size_t)blk * 256 + c;      // coalesced across the wave
        unsigned int tmp = bh[i];
        bh[i] = s;
        s += tmp;
    }
    __shared__ unsigned int tot[NCELL];
    tot[c] = s;
    __syncthreads();
    for (int d = 1; d < NCELL; d <<= 1) {
        unsigned int add = (c >= d) ? tot[c - d] : 0u;
        __syncthreads();
        tot[c] += add;
        __syncthreads();
    }
    cellBase[c] = tot[c] - s;   // exclusive
}

// Sort step 3: scatter with LDS-only ranks (zero global atomics).
__global__ void k_scat(const float* __restrict__ anchors,
                       const unsigned int* __restrict__ bh,
                       const unsigned int* __restrict__ cellBase,
                       float* __restrict__ sortedA,
                       int* __restrict__ orig, int A) {
    __shared__ unsigned int h[NCELL];
    int t = threadIdx.x;
    h[t] = 0u;
    __syncthreads();
    int a = blockIdx.x * 256 + t;
    if (a < A) {
        float4 ab = ((const float4*)anchors)[a];
        int c = cell_of(ab);
        unsigned int lr = atomicAdd(&h[c], 1u);          // LDS only
        unsigned int pos = cellBase[c] + bh[(size_t)blockIdx.x * 256 + c] + lr;
        ((float4*)sortedA)[pos] = ab;
        orig[pos] = a;
    }
}

// Pass 1: 4 anchors/thread, g-outer, wave-bbox pre-skip + inner ballot skip,
// DPP wave max, LDS block max. STORE: per-anchor vmax/amax + sred dump.
// Grid: (nchunks = ceil(A/1024), B), block 256.
template <bool STORE>
__global__ __launch_bounds__(256, 4)
void pass1_k(const float* __restrict__ gt,
             const float* __restrict__ anchors,
             const float* __restrict__ gab,
             unsigned int* __restrict__ hpg,
             unsigned int* __restrict__ sredg,
             float* __restrict__ vmaxA,
             int* __restrict__ amaxA,
             int A, int nchunks) {
    const int b = blockIdx.y;
    const int t = threadIdx.x;

    __shared__ unsigned int sred[G];
    if (t < G) sred[t] = 0u;
    __syncthreads();

    const int base = blockIdx.x * 1024;
    float ax1[4], ay1[4], ax2[4], ay2[4], aar[4];
    bool val[4];
#pragma unroll
    for (int k = 0; k < 4; ++k) {
        int a = base + k * 256 + t;
        val[k] = (a < A);
        float4 ab = ((const float4*)anchors)[val[k] ? a : 0];
        ax1[k] = val[k] ? ab.x : 3.0e38f;    // invalid -> +inf-ish corners:
        ay1[k] = val[k] ? ab.y : 3.0e38f;    //   x1>x2 -> w=0 -> inter=+0,
        ax2[k] = val[k] ? ab.z : -3.0e38f;   //   aar=(neg)*(neg)=huge? see aar fix
        ay2[k] = val[k] ? ab.w : -3.0e38f;
        aar[k] = val[k] ? box_area(ax1[k], ay1[k], ax2[k], ay2[k]) : 0.0f;
    }
    // NOTE invalid lanes: inter = max(rb-lt,0)=0 (rb=-3e38 < lt) and aar=0,
    // so q = 0/(ga+0-0) = +0.0 exactly; never affects maxes.

    // Wave bbox of this wave's 4*64 anchors (invalid lanes excluded by
    // +inf/-inf-style corners -> they can't extend the max/min wrong way
    // for x2/y2; x1/y1 use min over valid = min(3e38, valid) = valid).
    float wx1 = fminf(fminf(ax1[0], ax1[1]), fminf(ax1[2], ax1[3]));
    float wy1 = fminf(fminf(ay1[0], ay1[1]), fminf(ay1[2], ay1[3]));
    float wx2 = fmaxf(fmaxf(ax2[0], ax2[1]), fmaxf(ax2[2], ax2[3]));
    float wy2 = fmaxf(fmaxf(ay2[0], ay2[1]), fmaxf(ay2[2], ay2[3]));
    wx1 = lane63_bcast(wave_min_lane63(wx1));
    wy1 = lane63_bcast(wave_min_lane63(wy1));
    wx2 = lane63_bcast(wave_max_lane63(wx2));
    wy2 = lane63_bcast(wave_max_lane63(wy2));

    const float4* gtb = (const float4*)gt + (size_t)b * G;
    const float* gas = gab + b * G;

    float vmax[4] = {0.0f, 0.0f, 0.0f, 0.0f};
    int amax[4] = {0, 0, 0, 0};

#pragma unroll 4
    for (int g = 0; g < G; ++g) {
        const int gv = vindex(g);              // VMEM broadcast (L1-hot)
        const float4 gb = gtb[gv];
        // wave-uniform bbox test (~8 VALU): skips the whole body
        float tlx = fmaxf(gb.x, wx1), trx = fminf(gb.z, wx2);
        float tly = fmaxf(gb.y, wy1), tby = fminf(gb.w, wy2);
        if ((trx > tlx) && (tby > tly)) {
            float inter[4];
#pragma unroll
            for (int k = 0; k < 4; ++k)
                inter[k] = inter_area(gb.x, gb.y, gb.z, gb.w,
                                      ax1[k], ay1[k], ax2[k], ay2[k]);
            float itest = fmaxf(fmaxf(inter[0], inter[1]),
                                fmaxf(inter[2], inter[3]));
            if (__any(itest > 0.0f)) {
                const float ga = gas[gv];
                float m = 0.0f;
#pragma unroll
                for (int k = 0; k < 4; ++k) {
                    float denom = __fsub_rn(__fadd_rn(ga, aar[k]), inter[k]);
                    float q = div_rn(inter[k], denom);
                    if constexpr (STORE) {
                        if (q > vmax[k]) { vmax[k] = q; amax[k] = g; }
                    }
                    m = fmaxf(m, q);
                }
                m = wave_max_lane63(m);
                if ((t & 63) == 63)
                    atomicMax(&sred[g], __float_as_uint(m));
            }
        }
    }

    if constexpr (STORE) {
#pragma unroll
        for (int k = 0; k < 4; ++k) {
            if (!val[k]) continue;
            size_t idx = (size_t)b * A + (base + k * 256 + t);
            vmaxA[idx] = vmax[k];
            amaxA[idx] = amax[k];
        }
    }

    __syncthreads();
    if (t < G) {
        atomicMax(&hpg[b * G + t], sred[t]);
        if constexpr (STORE)
            sredg[(size_t)(b * nchunks + blockIdx.x) * G + t] = sred[t];
    }
}

// Pass 2 (E-mask fixup + scatter to orig order). Grid: (nchunks, B).
template <bool SCATTER>
__global__ __launch_bounds__(256, 8)
void pass2_lite(const float* __restrict__ gt,
                const float* __restrict__ anchors,
                const float* __restrict__ gab,
                const unsigned int* __restrict__ hpg,
                const unsigned int* __restrict__ sredg,
                const float* __restrict__ vmaxA,
                const int* __restrict__ amaxA,
                const int* __restrict__ orig,
                float* __restrict__ out_idx,
                float* __restrict__ out_val,
                int A, int nchunks) {
    const int b = blockIdx.y;
    const int t = threadIdx.x;
    const int base = blockIdx.x * 1024;

    const unsigned int* sb = sredg + (size_t)(b * nchunks + blockIdx.x) * G;
    const unsigned int* hb = hpg + b * G;

    unsigned long long E = 0ull;
#pragma unroll 16
    for (int g = 0; g < G; ++g)
        E |= (sb[g] == hb[g]) ? (1ull << g) : 0ull;

    bool pu[4] = {false, false, false, false};

    if (E != 0ull) {                    // rare; block-uniform branch
        const float4* gtb = (const float4*)gt + (size_t)b * G;
        const float* gas = gab + b * G;
        float ax1[4], ay1[4], ax2[4], ay2[4], aar[4];
#pragma unroll
        for (int k = 0; k < 4; ++k) {
            int a = base + k * 256 + t;
            bool v = (a < A);
            float4 ab = ((const float4*)anchors)[v ? a : 0];
            ax1[k] = v ? ab.x : 3.0e38f;
            ay1[k] = v ? ab.y : 3.0e38f;
            ax2[k] = v ? ab.z : -3.0e38f;
            ay2[k] = v ? ab.w : -3.0e38f;
            aar[k] = v ? box_area(ax1[k], ay1[k], ax2[k], ay2[k]) : 0.0f;
        }
        unsigned long long e = E;
        while (e) {
            int g = __builtin_ctzll(e);
            e &= e - 1;
            float4 gb = gtb[g];
            float ga = gas[g];
            float hgf = __uint_as_float(hb[g]);
#pragma unroll
            for (int k = 0; k < 4; ++k) {
                float inter = inter_area(gb.x, gb.y, gb.z, gb.w,
                                         ax1[k], ay1[k], ax2[k], ay2[k]);
                float denom = __fsub_rn(__fadd_rn(ga, aar[k]), inter);
                float q = div_rn(inter, denom);
                pu[k] = pu[k] | (q == hgf);
            }
        }
    }

#pragma unroll
    for (int k = 0; k < 4; ++k) {
        int a = base + k * 256 + t;
        if (a >= A) continue;
        size_t idx = (size_t)b * A + a;
        float vm = vmaxA[idx];
        int am = amaxA[idx];
        int m;
        if (pu[k]) {
            m = am;                          // low-quality match recovery
        } else if (vm < 0.4f) {
            m = -1;                          // BELOW_LOW_QUALITY
        } else if (vm < 0.5f) {
            m = -2;                          // BETWEEN_THRESHOLDS
        } else {
            m = am;
        }
        size_t o = SCATTER ? ((size_t)b * A + orig[a]) : idx;
        out_idx[o] = (float)m;
        out_val[o] = vm;
    }
}

extern "C" void kernel_launch(void* const* d_in, const int* in_sizes, int n_in,
                              void* d_out, int out_size, void* d_ws, size_t ws_size,
                              hipStream_t stream) {
    const float* gt = (const float*)d_in[0];
    const float* anchors = (const float*)d_in[1];
    const int BG = in_sizes[0] / 4;   // B*G = 512
    const int B = BG / G;             // 8
    const int A = in_sizes[1] / 4;    // 120000

    const int nchunks = (A + 1023) / 1024;
    const int NB = (A + 255) / 256;   // sort-kernel blocks

    // ws layout (u32 units, 16B-aligned where needed):
    // [0,512) hpg | [512,1024) gab | [1024,1280) cellBase |
    // [1280, +NB*256) bh | (align4) sortedA 4A | orig A |
    // sredg nchunks*B*64 | vmaxA B*A | amaxA B*A
    unsigned int* ws = (unsigned int*)d_ws;
    unsigned int* hpg = ws;
    float* gab = (float*)(ws + 512);
    unsigned int* cellBase = ws + 1024;
    unsigned int* bh = ws + 1280;
    size_t soff = 1280 + (size_t)NB * 256;
    soff = (soff + 3) & ~(size_t)3;                 // 16B align for float4
    float* sortedA = (float*)(ws + soff);
    int* orig = (int*)(ws + soff + 4 * (size_t)A);
    unsigned int* sredg = ws + soff + 5 * (size_t)A;
    size_t voff = soff + 5 * (size_t)A + (size_t)nchunks * B * G;
    float* vmaxA = (float*)(ws + voff);
    int* amaxA = (int*)(vmaxA + (size_t)B * A);
    const size_t need = (voff + 2 * (size_t)B * A) * 4;
    const bool sorted = (ws_size >= need);

    float* out_idx = (float*)d_out;
    float* out_val = out_idx + (size_t)B * A;

    k_init<<<(BG + 255) / 256, 256, 0, stream>>>(gt, hpg, gab, BG);

    dim3 g1(nchunks, B);
    if (sorted) {
        k_count<<<NB, 256, 0, stream>>>(anchors, bh, A);
        k_colscan<<<1, NCELL, 0, stream>>>(bh, cellBase, NB);
        k_scat<<<NB, 256, 0, stream>>>(anchors, bh, cellBase, sortedA, orig, A);
        pass1_k<true><<<g1, 256, 0, stream>>>(gt, sortedA, gab, hpg, sredg,
                                              vmaxA, amaxA, A, nchunks);
        pass2_lite<true><<<g1, 256, 0, stream>>>(gt, sortedA, gab, hpg, sredg,
                                                 vmaxA, amaxA, orig,
                                                 out_idx, out_val, A, nchunks);
    } else {
        // Fallback: R14 unsorted path (bbox skip rarely fires; still exact)
        pass1_k<true><<<g1, 256, 0, stream>>>(gt, anchors, gab, hpg, sredg,
                                              vmaxA, amaxA, A, nchunks);
        pass2_lite<false><<<g1, 256, 0, stream>>>(gt, anchors, gab, hpg, sredg,
                                                  vmaxA, amaxA, orig,
                                                  out_idx, out_val, A, nchunks);
    }
}

// Round 18
// 80.404 us; speedup vs baseline: 2.4115x; 1.3464x over previous
//
#include <hip/hip_runtime.h>

// RetinaNet matcher: gt_boxes [B=8, G=64, 4] f32, anchors [A=120000, 4] f32.
// Outputs (concat in d_out, f32): matched_idxs [B,A] (as float), matched_vals [B,A].
//
// Numerics: bit-exact vs np (absmax 0.0 R5-R17, incl. sorted path R16/R17).
// opaque() barriers on every mul -> no FMA-contraction site. div_rn() =
// correctly-rounded divide for mid-range operands. argmax tie-break = first g
// (strict >). IoU >= 0 -> uint atomicMax bit-exact.
//
// R18: R17's kernels are all <40us (fills crowd the profile top-5), so the
// 108-76 gap is the SERIAL k_colscan (1 block x 469 dependent iterations).
// Replace with a fully parallel scan: bh transposed to [c*NB+blk];
// k_rowscan = 256 independent blocks (one per cell) LDS-scanning their row;
// k_base = tiny 256-entry exclusive scan of cell totals. Zero global atomics
// anywhere in the sort. pass1_k / pass2_lite / k_init byte-identical to R17.

static constexpr int G = 64;
static constexpr int NCELL = 256;   // 16x16 grid of 50px cells

__device__ __forceinline__ float opaque(float x) {
    asm volatile("" : "+v"(x));  // no-op; blocks FMA contraction across x
    return x;
}

__device__ __forceinline__ int vindex(int i) {
    asm volatile("" : "+v"(i));  // force VGPR residency; defeats scalarization
    return i;
}

__device__ __forceinline__ float box_area(float x1, float y1, float x2, float y2) {
    return opaque(__fmul_rn(__fsub_rn(x2, x1), __fsub_rn(y2, y1)));
}

__device__ __forceinline__ float inter_area(float gx1, float gy1, float gx2, float gy2,
                                            float ax1, float ay1, float ax2, float ay2) {
    float ltx = fmaxf(gx1, ax1);
    float lty = fmaxf(gy1, ay1);
    float rbx = fminf(gx2, ax2);
    float rby = fminf(gy2, ay2);
    float w = fmaxf(__fsub_rn(rbx, ltx), 0.0f);
    float h = fmaxf(__fsub_rn(rby, lty), 0.0f);
    return opaque(__fmul_rn(w, h));
}

// Correctly-rounded f32 divide for mid-range operands (no denormal/overflow).
__device__ __forceinline__ float div_rn(float n, float d) {
    float r = __builtin_amdgcn_rcpf(d);
    float e = fmaf(-d, r, 1.0f);
    r = fmaf(e, r, r);
    float q = __fmul_rn(n, r);
    float s = fmaf(-d, q, n);
    q = fmaf(s, r, q);
    s = fmaf(-d, q, n);
    q = fmaf(s, r, q);
    return q;
}

#define DPP_MAX_STAGE(x, ctrl)                                                   \
    do {                                                                         \
        int _yi = __builtin_amdgcn_update_dpp(__float_as_int(x),                 \
                                              __float_as_int(x), (ctrl),         \
                                              0xf, 0xf, false);                  \
        (x) = fmaxf((x), __int_as_float(_yi));                                   \
    } while (0)

#define DPP_MIN_STAGE(x, ctrl)                                                   \
    do {                                                                         \
        int _yi = __builtin_amdgcn_update_dpp(__float_as_int(x),                 \
                                              __float_as_int(x), (ctrl),         \
                                              0xf, 0xf, false);                  \
        (x) = fminf((x), __int_as_float(_yi));                                   \
    } while (0)

// Full wave64 max; result valid in lane 63.
__device__ __forceinline__ float wave_max_lane63(float x) {
    DPP_MAX_STAGE(x, 0xB1);   // quad_perm xor1
    DPP_MAX_STAGE(x, 0x4E);   // quad_perm xor2
    DPP_MAX_STAGE(x, 0x141);  // row_half_mirror
    DPP_MAX_STAGE(x, 0x140);  // row_mirror
    DPP_MAX_STAGE(x, 0x142);  // row_bcast15
    DPP_MAX_STAGE(x, 0x143);  // row_bcast31
    return x;
}

__device__ __forceinline__ float wave_min_lane63(float x) {
    DPP_MIN_STAGE(x, 0xB1);
    DPP_MIN_STAGE(x, 0x4E);
    DPP_MIN_STAGE(x, 0x141);
    DPP_MIN_STAGE(x, 0x140);
    DPP_MIN_STAGE(x, 0x142);
    DPP_MIN_STAGE(x, 0x143);
    return x;
}

__device__ __forceinline__ float lane63_bcast(float x) {
    return __int_as_float(__builtin_amdgcn_readlane(__float_as_int(x), 63));
}

// hpg[i] = 0 bits (+0.0f) and gt-area cache for all (b,g).
__global__ void k_init(const float* __restrict__ gt, unsigned int* __restrict__ hpg,
                       float* __restrict__ gab, int BG) {
    int i = blockIdx.x * 256 + threadIdx.x;
    if (i < BG) {
        hpg[i] = 0u;
        float4 gb = ((const float4*)gt)[i];
        gab[i] = box_area(gb.x, gb.y, gb.z, gb.w);
    }
}

__device__ __forceinline__ int cell_of(float4 ab) {
    float cx = (ab.x + ab.z) * 0.5f;   // binning only; precision irrelevant
    float cy = (ab.y + ab.w) * 0.5f;
    int cxi = (int)(cx * 0.02f); cxi = cxi < 0 ? 0 : (cxi > 15 ? 15 : cxi);
    int cyi = (int)(cy * 0.02f); cyi = cyi < 0 ? 0 : (cyi > 15 ? 15 : cyi);
    return cyi * 16 + cxi;
}

// Sort step 1: per-block LDS histogram -> bh[c*NB + blk] (transposed).
__global__ void k_count(const float* __restrict__ anchors,
                        unsigned int* __restrict__ bh, int A, int NB) {
    __shared__ unsigned int h[NCELL];
    int t = threadIdx.x;
    h[t] = 0u;
    __syncthreads();
    int a = blockIdx.x * 256 + t;
    if (a < A) atomicAdd(&h[cell_of(((const float4*)anchors)[a])], 1u);
    __syncthreads();
    bh[(size_t)t * NB + blockIdx.x] = h[t];   // row t = cell t
}

// Sort step 2: 256 independent blocks; block c exclusive-scans row c of bh
// (length NB) via LDS Hillis-Steele chunks; writes total to cellTot[c].
__global__ void k_rowscan(unsigned int* __restrict__ bh,
                          unsigned int* __restrict__ cellTot, int NB) {
    const int c = blockIdx.x;
    unsigned int* row = bh + (size_t)c * NB;
    __shared__ unsigned int s[256];
    __shared__ unsigned int carry;
    if (threadIdx.x == 0) carry = 0u;
    __syncthreads();
    for (int base = 0; base < NB; base += 256) {
        int i = base + threadIdx.x;
        unsigned int v = (i < NB) ? row[i] : 0u;
        s[threadIdx.x] = v;
        __syncthreads();
        for (int d = 1; d < 256; d <<= 1) {
            unsigned int add = (threadIdx.x >= d) ? s[threadIdx.x - d] : 0u;
            __syncthreads();
            s[threadIdx.x] += add;
            __syncthreads();
        }
        unsigned int excl = s[threadIdx.x] - v + carry;   // uses OLD carry
        if (i < NB) row[i] = excl;
        __syncthreads();
        if (threadIdx.x == 255) carry += s[255];
        __syncthreads();
    }
    if (threadIdx.x == 0) cellTot[c] = carry;
}

// Sort step 3 (1 block): exclusive scan of cellTot -> cellBase.
__global__ void k_base(const unsigned int* __restrict__ cellTot,
                       unsigned int* __restrict__ cellBase) {
    __shared__ unsigned int s[NCELL];
    int t = threadIdx.x;
    unsigned int v = cellTot[t];
    s[t] = v;
    __syncthreads();
    for (int d = 1; d < NCELL; d <<= 1) {
        unsigned int add = (t >= d) ? s[t - d] : 0u;
        __syncthreads();
        s[t] += add;
        __syncthreads();
    }
    cellBase[t] = s[t] - v;   // exclusive
}

// Sort step 4: scatter with LDS-only ranks (zero global atomics).
__global__ void k_scat(const float* __restrict__ anchors,
                       const unsigned int* __restrict__ bh,
                       const unsigned int* __restrict__ cellBase,
                       float* __restrict__ sortedA,
                       int* __restrict__ orig, int A, int NB) {
    __shared__ unsigned int h[NCELL];
    int t = threadIdx.x;
    h[t] = 0u;
    __syncthreads();
    int a = blockIdx.x * 256 + t;
    if (a < A) {
        float4 ab = ((const float4*)anchors)[a];
        int c = cell_of(ab);
        unsigned int lr = atomicAdd(&h[c], 1u);          // LDS only
        unsigned int pos = cellBase[c] + bh[(size_t)c * NB + blockIdx.x] + lr;
        ((float4*)sortedA)[pos] = ab;
        orig[pos] = a;
    }
}

// Pass 1 (R17 verbatim): 4 anchors/thread, g-outer, wave-bbox pre-skip +
// inner ballot skip, DPP wave max, LDS block max. STORE: vmax/amax + sred.
// Grid: (nchunks = ceil(A/1024), B), block 256.
template <bool STORE>
__global__ __launch_bounds__(256, 4)
void pass1_k(const float* __restrict__ gt,
             const float* __restrict__ anchors,
             const float* __restrict__ gab,
             unsigned int* __restrict__ hpg,
             unsigned int* __restrict__ sredg,
             float* __restrict__ vmaxA,
             int* __restrict__ amaxA,
             int A, int nchunks) {
    const int b = blockIdx.y;
    const int t = threadIdx.x;

    __shared__ unsigned int sred[G];
    if (t < G) sred[t] = 0u;
    __syncthreads();

    const int base = blockIdx.x * 1024;
    float ax1[4], ay1[4], ax2[4], ay2[4], aar[4];
    bool val[4];
#pragma unroll
    for (int k = 0; k < 4; ++k) {
        int a = base + k * 256 + t;
        val[k] = (a < A);
        float4 ab = ((const float4*)anchors)[val[k] ? a : 0];
        ax1[k] = val[k] ? ab.x : 3.0e38f;    // invalid: x1>x2 -> inter==+0
        ay1[k] = val[k] ? ab.y : 3.0e38f;
        ax2[k] = val[k] ? ab.z : -3.0e38f;
        ay2[k] = val[k] ? ab.w : -3.0e38f;
        aar[k] = val[k] ? box_area(ax1[k], ay1[k], ax2[k], ay2[k]) : 0.0f;
    }
    // invalid lanes: inter=0, aar=0 -> q = 0/ga = +0.0 exactly; never affects maxes.

    float wx1 = fminf(fminf(ax1[0], ax1[1]), fminf(ax1[2], ax1[3]));
    float wy1 = fminf(fminf(ay1[0], ay1[1]), fminf(ay1[2], ay1[3]));
    float wx2 = fmaxf(fmaxf(ax2[0], ax2[1]), fmaxf(ax2[2], ax2[3]));
    float wy2 = fmaxf(fmaxf(ay2[0], ay2[1]), fmaxf(ay2[2], ay2[3]));
    wx1 = lane63_bcast(wave_min_lane63(wx1));
    wy1 = lane63_bcast(wave_min_lane63(wy1));
    wx2 = lane63_bcast(wave_max_lane63(wx2));
    wy2 = lane63_bcast(wave_max_lane63(wy2));

    const float4* gtb = (const float4*)gt + (size_t)b * G;
    const float* gas = gab + b * G;

    float vmax[4] = {0.0f, 0.0f, 0.0f, 0.0f};
    int amax[4] = {0, 0, 0, 0};

#pragma unroll 4
    for (int g = 0; g < G; ++g) {
        const int gv = vindex(g);              // VMEM broadcast (L1-hot)
        const float4 gb = gtb[gv];
        float tlx = fmaxf(gb.x, wx1), trx = fminf(gb.z, wx2);
        float tly = fmaxf(gb.y, wy1), tby = fminf(gb.w, wy2);
        if ((trx > tlx) && (tby > tly)) {      // wave-uniform bbox test
            float inter[4];
#pragma unroll
            for (int k = 0; k < 4; ++k)
                inter[k] = inter_area(gb.x, gb.y, gb.z, gb.w,
                                      ax1[k], ay1[k], ax2[k], ay2[k]);
            float itest = fmaxf(fmaxf(inter[0], inter[1]),
                                fmaxf(inter[2], inter[3]));
            if (__any(itest > 0.0f)) {
                const float ga = gas[gv];
                float m = 0.0f;
#pragma unroll
                for (int k = 0; k < 4; ++k) {
                    float denom = __fsub_rn(__fadd_rn(ga, aar[k]), inter[k]);
                    float q = div_rn(inter[k], denom);
                    if constexpr (STORE) {
                        if (q > vmax[k]) { vmax[k] = q; amax[k] = g; }
                    }
                    m = fmaxf(m, q);
                }
                m = wave_max_lane63(m);
                if ((t & 63) == 63)
                    atomicMax(&sred[g], __float_as_uint(m));
            }
        }
    }

    if constexpr (STORE) {
#pragma unroll
        for (int k = 0; k < 4; ++k) {
            if (!val[k]) continue;
            size_t idx = (size_t)b * A + (base + k * 256 + t);
            vmaxA[idx] = vmax[k];
            amaxA[idx] = amax[k];
        }
    }

    __syncthreads();
    if (t < G) {
        atomicMax(&hpg[b * G + t], sred[t]);
        if constexpr (STORE)
            sredg[(size_t)(b * nchunks + blockIdx.x) * G + t] = sred[t];
    }
}

// Pass 2 (R17 verbatim): E-mask fixup + scatter to orig order.
template <bool SCATTER>
__global__ __launch_bounds__(256, 8)
void pass2_lite(const float* __restrict__ gt,
                const float* __restrict__ anchors,
                const float* __restrict__ gab,
                const unsigned int* __restrict__ hpg,
                const unsigned int* __restrict__ sredg,
                const float* __restrict__ vmaxA,
                const int* __restrict__ amaxA,
                const int* __restrict__ orig,
                float* __restrict__ out_idx,
                float* __restrict__ out_val,
                int A, int nchunks) {
    const int b = blockIdx.y;
    const int t = threadIdx.x;
    const int base = blockIdx.x * 1024;

    const unsigned int* sb = sredg + (size_t)(b * nchunks + blockIdx.x) * G;
    const unsigned int* hb = hpg + b * G;

    unsigned long long E = 0ull;
#pragma unroll 16
    for (int g = 0; g < G; ++g)
        E |= (sb[g] == hb[g]) ? (1ull << g) : 0ull;

    bool pu[4] = {false, false, false, false};

    if (E != 0ull) {                    // rare; block-uniform branch
        const float4* gtb = (const float4*)gt + (size_t)b * G;
        const float* gas = gab + b * G;
        float ax1[4], ay1[4], ax2[4], ay2[4], aar[4];
#pragma unroll
        for (int k = 0; k < 4; ++k) {
            int a = base + k * 256 + t;
            bool v = (a < A);
            float4 ab = ((const float4*)anchors)[v ? a : 0];
            ax1[k] = v ? ab.x : 3.0e38f;
            ay1[k] = v ? ab.y : 3.0e38f;
            ax2[k] = v ? ab.z : -3.0e38f;
            ay2[k] = v ? ab.w : -3.0e38f;
            aar[k] = v ? box_area(ax1[k], ay1[k], ax2[k], ay2[k]) : 0.0f;
        }
        unsigned long long e = E;
        while (e) {
            int g = __builtin_ctzll(e);
            e &= e - 1;
            float4 gb = gtb[g];
            float ga = gas[g];
            float hgf = __uint_as_float(hb[g]);
#pragma unroll
            for (int k = 0; k < 4; ++k) {
                float inter = inter_area(gb.x, gb.y, gb.z, gb.w,
                                         ax1[k], ay1[k], ax2[k], ay2[k]);
                float denom = __fsub_rn(__fadd_rn(ga, aar[k]), inter);
                float q = div_rn(inter, denom);
                pu[k] = pu[k] | (q == hgf);
            }
        }
    }

#pragma unroll
    for (int k = 0; k < 4; ++k) {
        int a = base + k * 256 + t;
        if (a >= A) continue;
        size_t idx = (size_t)b * A + a;
        float vm = vmaxA[idx];
        int am = amaxA[idx];
        int m;
        if (pu[k]) {
            m = am;                          // low-quality match recovery
        } else if (vm < 0.4f) {
            m = -1;                          // BELOW_LOW_QUALITY
        } else if (vm < 0.5f) {
            m = -2;                          // BETWEEN_THRESHOLDS
        } else {
            m = am;
        }
        size_t o = SCATTER ? ((size_t)b * A + orig[a]) : idx;
        out_idx[o] = (float)m;
        out_val[o] = vm;
    }
}

extern "C" void kernel_launch(void* const* d_in, const int* in_sizes, int n_in,
                              void* d_out, int out_size, void* d_ws, size_t ws_size,
                              hipStream_t stream) {
    const float* gt = (const float*)d_in[0];
    const float* anchors = (const float*)d_in[1];
    const int BG = in_sizes[0] / 4;   // B*G = 512
    const int B = BG / G;             // 8
    const int A = in_sizes[1] / 4;    // 120000

    const int nchunks = (A + 1023) / 1024;
    const int NB = (A + 255) / 256;   // sort-kernel blocks

    // ws layout (u32 units):
    // [0,512) hpg | [512,1024) gab | [1024,1280) cellBase | [1280,1536) cellTot |
    // [1536, +NB*256) bh | (align4) sortedA 4A | orig A |
    // sredg nchunks*B*64 | vmaxA B*A | amaxA B*A
    unsigned int* ws = (unsigned int*)d_ws;
    unsigned int* hpg = ws;
    float* gab = (float*)(ws + 512);
    unsigned int* cellBase = ws + 1024;
    unsigned int* cellTot = ws + 1280;
    unsigned int* bh = ws + 1536;
    size_t soff = 1536 + (size_t)NB * 256;
    soff = (soff + 3) & ~(size_t)3;                 // 16B align for float4
    float* sortedA = (float*)(ws + soff);
    int* orig = (int*)(ws + soff + 4 * (size_t)A);
    unsigned int* sredg = ws + soff + 5 * (size_t)A;
    size_t voff = soff + 5 * (size_t)A + (size_t)nchunks * B * G;
    float* vmaxA = (float*)(ws + voff);
    int* amaxA = (int*)(vmaxA + (size_t)B * A);
    const size_t need = (voff + 2 * (size_t)B * A) * 4;
    const bool sorted = (ws_size >= need);

    float* out_idx = (float*)d_out;
    float* out_val = out_idx + (size_t)B * A;

    k_init<<<(BG + 255) / 256, 256, 0, stream>>>(gt, hpg, gab, BG);

    dim3 g1(nchunks, B);
    if (sorted) {
        k_count<<<NB, 256, 0, stream>>>(anchors, bh, A, NB);
        k_rowscan<<<NCELL, 256, 0, stream>>>(bh, cellTot, NB);
        k_base<<<1, NCELL, 0, stream>>>(cellTot, cellBase);
        k_scat<<<NB, 256, 0, stream>>>(anchors, bh, cellBase, sortedA, orig, A, NB);
        pass1_k<true><<<g1, 256, 0, stream>>>(gt, sortedA, gab, hpg, sredg,
                                              vmaxA, amaxA, A, nchunks);
        pass2_lite<true><<<g1, 256, 0, stream>>>(gt, sortedA, gab, hpg, sredg,
                                                 vmaxA, amaxA, orig,
                                                 out_idx, out_val, A, nchunks);
    } else {
        // Fallback: unsorted path (bbox test still correct, rarely fires)
        pass1_k<true><<<g1, 256, 0, stream>>>(gt, anchors, gab, hpg, sredg,
                                              vmaxA, amaxA, A, nchunks);
        pass2_lite<false><<<g1, 256, 0, stream>>>(gt, anchors, gab, hpg, sredg,
                                                  vmaxA, amaxA, orig,
                                                  out_idx, out_val, A, nchunks);
    }
}

// Round 19
// 68.337 us; speedup vs baseline: 2.8373x; 1.1766x over previous
//
#include <hip/hip_runtime.h>

// RetinaNet matcher: gt_boxes [B=8, G=64, 4] f32, anchors [A=120000, 4] f32.
// Outputs (concat in d_out, f32): matched_idxs [B,A] (as float), matched_vals [B,A].
//
// Numerics: bit-exact vs np (absmax 0.0 R5-R18, incl. sorted path R16-R18).
// opaque() barriers on every mul -> no FMA-contraction site. div_rn() =
// correctly-rounded divide for mid-range operands. argmax tie-break = first g
// (strict >). IoU >= 0 -> uint atomicMax bit-exact.
//
// R19: strip plumbing from R18 (80.4) which trails R14 (76.1) despite a
// cheaper pass1. (1) k_init merged into k_count. (2) k_base merged into
// k_scat (per-block LDS scan of cellTot). (3) pass1 writes FINAL outputs
// directly (tentative m with pu=false; out_val=vmax) scattered via orig,
// keeps only amaxA; pass2 becomes k_patch: exit-if-E==0 (~58% of blocks),
// else recompute q for E-set g's only and overwrite out_idx=amax where pu.
// pu-true & vmax>=0.5 rewrites the same value (harmless). hpg==0 rows:
// E-bit set everywhere, q=+0.0==hpg exact, amax=0=np.argmax. orig is a
// bijection -> every output written once by pass1; deterministic replay.

static constexpr int G = 64;
static constexpr int NCELL = 256;   // 16x16 grid of 50px cells

__device__ __forceinline__ float opaque(float x) {
    asm volatile("" : "+v"(x));  // no-op; blocks FMA contraction across x
    return x;
}

__device__ __forceinline__ int vindex(int i) {
    asm volatile("" : "+v"(i));  // force VGPR residency; defeats scalarization
    return i;
}

__device__ __forceinline__ float box_area(float x1, float y1, float x2, float y2) {
    return opaque(__fmul_rn(__fsub_rn(x2, x1), __fsub_rn(y2, y1)));
}

__device__ __forceinline__ float inter_area(float gx1, float gy1, float gx2, float gy2,
                                            float ax1, float ay1, float ax2, float ay2) {
    float ltx = fmaxf(gx1, ax1);
    float lty = fmaxf(gy1, ay1);
    float rbx = fminf(gx2, ax2);
    float rby = fminf(gy2, ay2);
    float w = fmaxf(__fsub_rn(rbx, ltx), 0.0f);
    float h = fmaxf(__fsub_rn(rby, lty), 0.0f);
    return opaque(__fmul_rn(w, h));
}

// Correctly-rounded f32 divide for mid-range operands (no denormal/overflow).
__device__ __forceinline__ float div_rn(float n, float d) {
    float r = __builtin_amdgcn_rcpf(d);
    float e = fmaf(-d, r, 1.0f);
    r = fmaf(e, r, r);
    float q = __fmul_rn(n, r);
    float s = fmaf(-d, q, n);
    q = fmaf(s, r, q);
    s = fmaf(-d, q, n);
    q = fmaf(s, r, q);
    return q;
}

#define DPP_MAX_STAGE(x, ctrl)                                                   \
    do {                                                                         \
        int _yi = __builtin_amdgcn_update_dpp(__float_as_int(x),                 \
                                              __float_as_int(x), (ctrl),         \
                                              0xf, 0xf, false);                  \
        (x) = fmaxf((x), __int_as_float(_yi));                                   \
    } while (0)

#define DPP_MIN_STAGE(x, ctrl)                                                   \
    do {                                                                         \
        int _yi = __builtin_amdgcn_update_dpp(__float_as_int(x),                 \
                                              __float_as_int(x), (ctrl),         \
                                              0xf, 0xf, false);                  \
        (x) = fminf((x), __int_as_float(_yi));                                   \
    } while (0)

// Full wave64 max; result valid in lane 63.
__device__ __forceinline__ float wave_max_lane63(float x) {
    DPP_MAX_STAGE(x, 0xB1);   // quad_perm xor1
    DPP_MAX_STAGE(x, 0x4E);   // quad_perm xor2
    DPP_MAX_STAGE(x, 0x141);  // row_half_mirror
    DPP_MAX_STAGE(x, 0x140);  // row_mirror
    DPP_MAX_STAGE(x, 0x142);  // row_bcast15
    DPP_MAX_STAGE(x, 0x143);  // row_bcast31
    return x;
}

__device__ __forceinline__ float wave_min_lane63(float x) {
    DPP_MIN_STAGE(x, 0xB1);
    DPP_MIN_STAGE(x, 0x4E);
    DPP_MIN_STAGE(x, 0x141);
    DPP_MIN_STAGE(x, 0x140);
    DPP_MIN_STAGE(x, 0x142);
    DPP_MIN_STAGE(x, 0x143);
    return x;
}

__device__ __forceinline__ float lane63_bcast(float x) {
    return __int_as_float(__builtin_amdgcn_readlane(__float_as_int(x), 63));
}

__device__ __forceinline__ int cell_of(float4 ab) {
    float cx = (ab.x + ab.z) * 0.5f;   // binning only; precision irrelevant
    float cy = (ab.y + ab.w) * 0.5f;
    int cxi = (int)(cx * 0.02f); cxi = cxi < 0 ? 0 : (cxi > 15 ? 15 : cxi);
    int cyi = (int)(cy * 0.02f); cyi = cyi < 0 ? 0 : (cyi > 15 ? 15 : cyi);
    return cyi * 16 + cxi;
}

// Sort step 1 (+init): per-block LDS hist -> bh[c*NB+blk]; blocks 0,1 also
// zero hpg and fill gab (BG = 512 <= 2*256).
__global__ void k_count(const float* __restrict__ gt,
                        const float* __restrict__ anchors,
                        unsigned int* __restrict__ bh,
                        unsigned int* __restrict__ hpg,
                        float* __restrict__ gab,
                        int A, int NB, int BG) {
    int t = threadIdx.x;
    int gi = blockIdx.x * 256 + t;
    if (gi < BG) {                      // init (blocks 0..1 only)
        hpg[gi] = 0u;
        float4 gb = ((const float4*)gt)[gi];
        gab[gi] = box_area(gb.x, gb.y, gb.z, gb.w);
    }
    __shared__ unsigned int h[NCELL];
    h[t] = 0u;
    __syncthreads();
    int a = blockIdx.x * 256 + t;
    if (a < A) atomicAdd(&h[cell_of(((const float4*)anchors)[a])], 1u);
    __syncthreads();
    bh[(size_t)t * NB + blockIdx.x] = h[t];   // row t = cell t
}

// Sort step 2: 256 independent blocks; block c exclusive-scans row c of bh
// (length NB) via LDS Hillis-Steele chunks; writes total to cellTot[c].
__global__ void k_rowscan(unsigned int* __restrict__ bh,
                          unsigned int* __restrict__ cellTot, int NB) {
    const int c = blockIdx.x;
    unsigned int* row = bh + (size_t)c * NB;
    __shared__ unsigned int s[256];
    __shared__ unsigned int carry;
    if (threadIdx.x == 0) carry = 0u;
    __syncthreads();
    for (int base = 0; base < NB; base += 256) {
        int i = base + threadIdx.x;
        unsigned int v = (i < NB) ? row[i] : 0u;
        s[threadIdx.x] = v;
        __syncthreads();
        for (int d = 1; d < 256; d <<= 1) {
            unsigned int add = (threadIdx.x >= d) ? s[threadIdx.x - d] : 0u;
            __syncthreads();
            s[threadIdx.x] += add;
            __syncthreads();
        }
        unsigned int excl = s[threadIdx.x] - v + carry;   // uses OLD carry
        if (i < NB) row[i] = excl;
        __syncthreads();
        if (threadIdx.x == 255) carry += s[255];
        __syncthreads();
    }
    if (threadIdx.x == 0) cellTot[c] = carry;
}

// Sort step 3 (+base): scatter with LDS-only ranks; cellBase computed
// in-block from cellTot by a 256-wide LDS scan (cheap, parallel).
__global__ void k_scat(const float* __restrict__ anchors,
                       const unsigned int* __restrict__ bh,
                       const unsigned int* __restrict__ cellTot,
                       float* __restrict__ sortedA,
                       int* __restrict__ orig, int A, int NB) {
    __shared__ unsigned int cb[NCELL];   // inclusive scan of cellTot
    __shared__ unsigned int tot[NCELL];
    __shared__ unsigned int h[NCELL];
    int t = threadIdx.x;
    unsigned int v = cellTot[t];
    cb[t] = v;
    tot[t] = v;
    h[t] = 0u;
    __syncthreads();
    for (int d = 1; d < NCELL; d <<= 1) {
        unsigned int add = (t >= d) ? cb[t - d] : 0u;
        __syncthreads();
        cb[t] += add;
        __syncthreads();
    }
    int a = blockIdx.x * 256 + t;
    if (a < A) {
        float4 ab = ((const float4*)anchors)[a];
        int c = cell_of(ab);
        unsigned int lr = atomicAdd(&h[c], 1u);          // LDS only
        unsigned int base = cb[c] - tot[c];              // exclusive cellBase
        unsigned int pos = base + bh[(size_t)c * NB + blockIdx.x] + lr;
        ((float4*)sortedA)[pos] = ab;
        orig[pos] = a;
    }
}

// Pass 1: 4 anchors/thread, g-outer, wave-bbox pre-skip + inner ballot skip,
// DPP wave max, LDS block max. Writes FINAL tentative outputs (pu=false)
// scattered via orig, plus amaxA (sorted-order, coalesced) and sred dump.
// Grid: (nchunks = ceil(A/1024), B), block 256.
template <bool SCATTER>
__global__ __launch_bounds__(256, 4)
void pass1_k(const float* __restrict__ gt,
             const float* __restrict__ anchors,
             const float* __restrict__ gab,
             unsigned int* __restrict__ hpg,
             unsigned int* __restrict__ sredg,
             int* __restrict__ amaxA,
             const int* __restrict__ orig,
             float* __restrict__ out_idx,
             float* __restrict__ out_val,
             int A, int nchunks) {
    const int b = blockIdx.y;
    const int t = threadIdx.x;

    __shared__ unsigned int sred[G];
    if (t < G) sred[t] = 0u;
    __syncthreads();

    const int base = blockIdx.x * 1024;
    float ax1[4], ay1[4], ax2[4], ay2[4], aar[4];
    bool val[4];
#pragma unroll
    for (int k = 0; k < 4; ++k) {
        int a = base + k * 256 + t;
        val[k] = (a < A);
        float4 ab = ((const float4*)anchors)[val[k] ? a : 0];
        ax1[k] = val[k] ? ab.x : 3.0e38f;    // invalid: x1>x2 -> inter==+0
        ay1[k] = val[k] ? ab.y : 3.0e38f;
        ax2[k] = val[k] ? ab.z : -3.0e38f;
        ay2[k] = val[k] ? ab.w : -3.0e38f;
        aar[k] = val[k] ? box_area(ax1[k], ay1[k], ax2[k], ay2[k]) : 0.0f;
    }
    // invalid lanes: inter=0, aar=0 -> q = +0.0 exactly; never affects maxes.

    float wx1 = fminf(fminf(ax1[0], ax1[1]), fminf(ax1[2], ax1[3]));
    float wy1 = fminf(fminf(ay1[0], ay1[1]), fminf(ay1[2], ay1[3]));
    float wx2 = fmaxf(fmaxf(ax2[0], ax2[1]), fmaxf(ax2[2], ax2[3]));
    float wy2 = fmaxf(fmaxf(ay2[0], ay2[1]), fmaxf(ay2[2], ay2[3]));
    wx1 = lane63_bcast(wave_min_lane63(wx1));
    wy1 = lane63_bcast(wave_min_lane63(wy1));
    wx2 = lane63_bcast(wave_max_lane63(wx2));
    wy2 = lane63_bcast(wave_max_lane63(wy2));

    const float4* gtb = (const float4*)gt + (size_t)b * G;
    const float* gas = gab + b * G;

    float vmax[4] = {0.0f, 0.0f, 0.0f, 0.0f};
    int amax[4] = {0, 0, 0, 0};

#pragma unroll 4
    for (int g = 0; g < G; ++g) {
        const int gv = vindex(g);              // VMEM broadcast (L1-hot)
        const float4 gb = gtb[gv];
        float tlx = fmaxf(gb.x, wx1), trx = fminf(gb.z, wx2);
        float tly = fmaxf(gb.y, wy1), tby = fminf(gb.w, wy2);
        if ((trx > tlx) && (tby > tly)) {      // wave-uniform bbox test
            float inter[4];
#pragma unroll
            for (int k = 0; k < 4; ++k)
                inter[k] = inter_area(gb.x, gb.y, gb.z, gb.w,
                                      ax1[k], ay1[k], ax2[k], ay2[k]);
            float itest = fmaxf(fmaxf(inter[0], inter[1]),
                                fmaxf(inter[2], inter[3]));
            if (__any(itest > 0.0f)) {
                const float ga = gas[gv];
                float m = 0.0f;
#pragma unroll
                for (int k = 0; k < 4; ++k) {
                    float denom = __fsub_rn(__fadd_rn(ga, aar[k]), inter[k]);
                    float q = div_rn(inter[k], denom);
                    if (q > vmax[k]) { vmax[k] = q; amax[k] = g; }  // first-max
                    m = fmaxf(m, q);
                }
                m = wave_max_lane63(m);
                if ((t & 63) == 63)
                    atomicMax(&sred[g], __float_as_uint(m));
            }
        }
    }

#pragma unroll
    for (int k = 0; k < 4; ++k) {
        if (!val[k]) continue;
        int a = base + k * 256 + t;
        size_t sidx = (size_t)b * A + a;
        amaxA[sidx] = amax[k];
        int mt;                                // tentative: pu assumed false
        if (vmax[k] < 0.4f) mt = -1;
        else if (vmax[k] < 0.5f) mt = -2;
        else mt = amax[k];
        int ao = SCATTER ? orig[a] : a;
        size_t o = (size_t)b * A + ao;
        out_idx[o] = (float)mt;
        out_val[o] = vmax[k];
    }

    __syncthreads();
    if (t < G) {
        atomicMax(&hpg[b * G + t], sred[t]);
        sredg[(size_t)(b * nchunks + blockIdx.x) * G + t] = sred[t];
    }
}

// Patch: E[g] = (sred_blk[g]==hpg[g]); exit if E==0 (common). Else recompute
// q for the E-set g's (bit-exact) and overwrite out_idx=amax where pu.
template <bool SCATTER>
__global__ __launch_bounds__(256, 8)
void k_patch(const float* __restrict__ gt,
             const float* __restrict__ anchors,
             const float* __restrict__ gab,
             const unsigned int* __restrict__ hpg,
             const unsigned int* __restrict__ sredg,
             const int* __restrict__ amaxA,
             const int* __restrict__ orig,
             float* __restrict__ out_idx,
             int A, int nchunks) {
    const int b = blockIdx.y;
    const int t = threadIdx.x;
    const int base = blockIdx.x * 1024;

    const unsigned int* sb = sredg + (size_t)(b * nchunks + blockIdx.x) * G;
    const unsigned int* hb = hpg + b * G;

    unsigned long long E = 0ull;
#pragma unroll 16
    for (int g = 0; g < G; ++g)
        E |= (sb[g] == hb[g]) ? (1ull << g) : 0ull;
    if (E == 0ull) return;              // common fast exit (block-uniform)

    const float4* gtb = (const float4*)gt + (size_t)b * G;
    const float* gas = gab + b * G;
    float ax1[4], ay1[4], ax2[4], ay2[4], aar[4];
    bool val[4];
#pragma unroll
    for (int k = 0; k < 4; ++k) {
        int a = base + k * 256 + t;
        val[k] = (a < A);
        float4 ab = ((const float4*)anchors)[val[k] ? a : 0];
        ax1[k] = val[k] ? ab.x : 3.0e38f;
        ay1[k] = val[k] ? ab.y : 3.0e38f;
        ax2[k] = val[k] ? ab.z : -3.0e38f;
        ay2[k] = val[k] ? ab.w : -3.0e38f;
        aar[k] = val[k] ? box_area(ax1[k], ay1[k], ax2[k], ay2[k]) : 0.0f;
    }

    bool pu[4] = {false, false, false, false};
    unsigned long long e = E;
    while (e) {
        int g = __builtin_ctzll(e);
        e &= e - 1;
        float4 gb = gtb[g];
        float ga = gas[g];
        float hgf = __uint_as_float(hb[g]);
#pragma unroll
        for (int k = 0; k < 4; ++k) {
            float inter = inter_area(gb.x, gb.y, gb.z, gb.w,
                                     ax1[k], ay1[k], ax2[k], ay2[k]);
            float denom = __fsub_rn(__fadd_rn(ga, aar[k]), inter);
            float q = div_rn(inter, denom);
            pu[k] = pu[k] | (q == hgf);
        }
    }

#pragma unroll
    for (int k = 0; k < 4; ++k) {
        int a = base + k * 256 + t;
        if (!val[k] || !pu[k]) continue;
        int ao = SCATTER ? orig[a] : a;
        out_idx[(size_t)b * A + ao] = (float)amaxA[(size_t)b * A + a];
    }
}

extern "C" void kernel_launch(void* const* d_in, const int* in_sizes, int n_in,
                              void* d_out, int out_size, void* d_ws, size_t ws_size,
                              hipStream_t stream) {
    const float* gt = (const float*)d_in[0];
    const float* anchors = (const float*)d_in[1];
    const int BG = in_sizes[0] / 4;   // B*G = 512
    const int B = BG / G;             // 8
    const int A = in_sizes[1] / 4;    // 120000

    const int nchunks = (A + 1023) / 1024;
    const int NB = (A + 255) / 256;   // sort-kernel blocks

    // ws layout (u32 units):
    // [0,512) hpg | [512,1024) gab | [1024,1280) cellTot |
    // [1280, +NB*256) bh | (align4) sortedA 4A | orig A |
    // sredg nchunks*B*64 | amaxA B*A
    unsigned int* ws = (unsigned int*)d_ws;
    unsigned int* hpg = ws;
    float* gab = (float*)(ws + 512);
    unsigned int* cellTot = ws + 1024;
    unsigned int* bh = ws + 1280;
    size_t soff = 1280 + (size_t)NB * 256;
    soff = (soff + 3) & ~(size_t)3;                 // 16B align for float4
    float* sortedA = (float*)(ws + soff);
    int* orig = (int*)(ws + soff + 4 * (size_t)A);
    unsigned int* sredg = ws + soff + 5 * (size_t)A;
    size_t aoff = soff + 5 * (size_t)A + (size_t)nchunks * B * G;
    int* amaxA = (int*)(ws + aoff);
    const size_t need = (aoff + (size_t)B * A) * 4;
    const bool sorted = (ws_size >= need);

    float* out_idx = (float*)d_out;
    float* out_val = out_idx + (size_t)B * A;

    dim3 g1(nchunks, B);
    if (sorted) {
        k_count<<<NB, 256, 0, stream>>>(gt, anchors, bh, hpg, gab, A, NB, BG);
        k_rowscan<<<NCELL, 256, 0, stream>>>(bh, cellTot, NB);
        k_scat<<<NB, 256, 0, stream>>>(anchors, bh, cellTot, sortedA, orig, A, NB);
        pass1_k<true><<<g1, 256, 0, stream>>>(gt, sortedA, gab, hpg, sredg,
                                              amaxA, orig, out_idx, out_val,
                                              A, nchunks);
        k_patch<true><<<g1, 256, 0, stream>>>(gt, sortedA, gab, hpg, sredg,
                                              amaxA, orig, out_idx, A, nchunks);
    } else {
        // Fallback: unsorted (orig = identity). Needs hpg/gab init: reuse
        // k_count's init blocks (histogram result unused but harmless).
        k_count<<<NB, 256, 0, stream>>>(gt, anchors, bh, hpg, gab, A, NB, BG);
        pass1_k<false><<<g1, 256, 0, stream>>>(gt, anchors, gab, hpg, sredg,
                                               amaxA, orig, out_idx, out_val,
                                               A, nchunks);
        k_patch<false><<<g1, 256, 0, stream>>>(gt, anchors, gab, hpg, sredg,
                                               amaxA, orig, out_idx, A, nchunks);
    }
}